// Round 6
// baseline (519.835 us; speedup 1.0000x reference)
//
#include <hip/hip_runtime.h>

// 4-layer 5-point cross-stencil CNN, implicit GEMM on MFMA (MI355X gfx950).
// Round 6: B-weights through LDS (double-buffered, 1 barrier/k-step).
// Round-5 counter model: B-from-L2 was the binding pipe (16 KB/block/k-step
// = 290 cyc vs 78 cyc MFMA). Staging B into LDS once per block removes the
// duplication and converts 4 L2 streams into LDS broadcast reads.
// LDS: A-panel 49.0 KB + B ping-pong 2x10.2 KB (oc stride padded 32->40,
// kills 8-way bank conflict) = 69.4 KB -> 2 blocks/CU.
// MFMA 16x16x32_f16 layouts (verified rounds 3-5):
//   A[m=lane&15][k=quad*8+j], B[n=lane&15][k=quad*8+j], C: col=lane&15,
//   row=quad*4+reg.   Taps: 0=c,1=up,2=down,3=left,4=right.

#define BB   8
#define HH   256
#define WW   256

typedef _Float16 f16x8 __attribute__((ext_vector_type(8)));
typedef float    f32x4 __attribute__((ext_vector_type(4)));

// K-major fp16 weight tables (rewritten every launch by prep).
__device__ _Float16 W1g[128 * 32];       // [oc][k], k=tap*6+ic, 30..31 = 0
__device__ _Float16 W2g[20 * 128 * 32];  // [ks=tap*4+kc][oc][icb]
__device__ _Float16 W3g[20 * 128 * 32];
__device__ _Float16 W4g[5 * 16 * 128];   // [tap][oc(pad16)][ic]

__global__ void prep(const float* __restrict__ w1, const float* __restrict__ w2,
                     const float* __restrict__ w3, const float* __restrict__ w4)
{
    int idx = blockIdx.x * 256 + threadIdx.x;
    if (idx < 81920) {                                  // W2g
        int icb = idx & 31, oc = (idx >> 5) & 127, ks = idx >> 12;
        int tap = ks >> 2, ic = (ks & 3) * 32 + icb;
        W2g[idx] = (_Float16)w2[(oc * 128 + ic) * 5 + tap];
    } else if (idx < 163840) {                          // W3g
        int k = idx - 81920;
        int icb = k & 31, oc = (k >> 5) & 127, ks = k >> 12;
        int tap = ks >> 2, ic = (ks & 3) * 32 + icb;
        W3g[k] = (_Float16)w3[(oc * 128 + ic) * 5 + tap];
    } else if (idx < 174080) {                          // W4g
        int k = idx - 163840;
        int t = k / 2048, oc = (k >> 7) & 15, ic = k & 127;
        W4g[k] = (_Float16)((oc < 6) ? w4[(oc * 128 + ic) * 5 + t] : 0.f);
    } else if (idx < 178176) {                          // W1g
        int k = idx - 174080;
        int kk = k & 31, oc = k >> 5;
        float v = 0.f;
        if (kk < 30) {
            int tap = (kk * 43) >> 8;                   // kk/6 for kk<30
            int ic = kk - 6 * tap;
            v = w1[(oc * 6 + ic) * 5 + tap];
        }
        W1g[k] = (_Float16)v;
    }
}

// ---------------- L1: MFMA, K=32 (tap*6+ic, padded). NCHW fp32 -> NHWC fp16.
__global__ __launch_bounds__(256, 3) void g1(
    const float* __restrict__ x, const float* __restrict__ bias,
    _Float16* __restrict__ outp)
{
    __shared__ _Float16 Ap[128 * 40];
    const int tid = threadIdx.x;
    const int j0 = blockIdx.x * 16, i0 = blockIdx.y * 8, b = blockIdx.z;
    const int px = tid & 127, half = tid >> 7;
    const int pr = px >> 4, pp = px & 15;
#pragma unroll
    for (int it = 0; it < 16; ++it) {
        int k = it * 2 + half;
        float v = 0.f;
        if (k < 30) {
            int tap = (k * 43) >> 8, ic = k - 6 * tap;
            int di = (tap == 1) ? -1 : ((tap == 2) ? 1 : 0);
            int dj = (tap == 3) ? -1 : ((tap == 4) ? 1 : 0);
            int gi = i0 + pr + di, gj = j0 + pp + dj;
            if (((unsigned)gi < 256u) && ((unsigned)gj < 256u))
                v = x[(((size_t)b * 6 + ic) * 256 + gi) * 256 + gj];
        }
        Ap[px * 40 + k] = (_Float16)v;
    }
    __syncthreads();

    const int lane = tid & 63, w = tid >> 6, l16 = lane & 15, quad = lane >> 4;
    f32x4 acc[2][8] = {};
    f16x8 a0 = *(const f16x8*)&Ap[((2 * w + 0) * 16 + l16) * 40 + quad * 8];
    f16x8 a1 = *(const f16x8*)&Ap[((2 * w + 1) * 16 + l16) * 40 + quad * 8];
#pragma unroll
    for (int nf = 0; nf < 8; ++nf) {
        f16x8 bf = *(const f16x8*)&W1g[(nf * 16 + l16) * 32 + quad * 8];
        acc[0][nf] = __builtin_amdgcn_mfma_f32_16x16x32_f16(a0, bf, acc[0][nf], 0, 0, 0);
        acc[1][nf] = __builtin_amdgcn_mfma_f32_16x16x32_f16(a1, bf, acc[1][nf], 0, 0, 0);
    }
#pragma unroll
    for (int mf = 0; mf < 2; ++mf) {
        const size_t rowb = ((size_t)b * 256 + i0 + 2 * w + mf) * 256 + j0;
#pragma unroll
        for (int nf = 0; nf < 8; ++nf) {
            const float bv = bias[nf * 16 + l16];
#pragma unroll
            for (int r = 0; r < 4; ++r)
                outp[(rowb + quad * 4 + r) * 128 + nf * 16 + l16] =
                    (_Float16)fmaxf(acc[mf][nf][r] + bv, 0.f);
        }
    }
}

// ---------------- middle layers: M=128 (8 rows x 16 px), N=128, K=640 -------
// 2x2 wave grid (wave: 4 rows x 64 oc). B staged into LDS ping-pong buffers.
template<int LAYER>
__global__ __launch_bounds__(256, 2) void gmid(
    const _Float16* __restrict__ in, const float* __restrict__ bias,
    _Float16* __restrict__ outp)
{
    const _Float16* wt = (LAYER == 2) ? W2g : W3g;
    __shared__ _Float16 Al[10 * 18 * 136];       // 48,960 B
    __shared__ _Float16 Bls[2][128 * 40];        // 2 x 10,240 B (stride 40: no conflicts)
    const int tid = threadIdx.x;
    const int j0 = blockIdx.x * 16, i0 = blockIdx.y * 8, b = blockIdx.z;

    // ---- stage A-halo panel (once) ----
    for (int t = tid; t < 2880; t += 256) {      // 10 rows x 18 px x 16 chunks
        int r = t / 288, rem = t - r * 288, p = rem >> 4, q = rem & 15;
        int gi = i0 - 1 + r, gj = j0 - 1 + p;
        f16x8 v = {0, 0, 0, 0, 0, 0, 0, 0};
        if (((unsigned)gi < 256u) && ((unsigned)gj < 256u))
            v = *(const f16x8*)&in[(((size_t)b * 256 + gi) * 256 + gj) * 128 + q * 8];
        *(f16x8*)&Al[(r * 18 + p) * 136 + q * 8] = v;
    }

    // ---- stage B tile for ks=0 into buffer 0 ----
    {
        const _Float16* src = wt + tid * 16;     // 4096 elems / 256 thr = 16
        f16x8 g0 = *(const f16x8*)src;
        f16x8 g1 = *(const f16x8*)(src + 8);
        _Float16* dst = &Bls[0][(tid >> 1) * 40 + (tid & 1) * 16];
        *(f16x8*)dst = g0;
        *(f16x8*)(dst + 8) = g1;
    }
    __syncthreads();

    const int lane = tid & 63, w = tid >> 6;
    const int l16 = lane & 15, quad = lane >> 4;
    const int mg = w & 1, ng = w >> 1;
    const int r0 = mg * 4;                       // first of 4 rows
    const int n0 = ng * 64;                      // first of 64 oc

    f32x4 acc[4][4] = {};
    const int DR[5] = {1, 0, 2, 1, 1}, DP[5] = {1, 1, 1, 0, 2};
    const int boff = (n0 + l16) * 40 + quad * 8; // B frag nf at + nf*640

#pragma unroll
    for (int ks = 0; ks < 20; ++ks) {
        f16x8 gn0, gn1;
        if (ks < 19) {                           // global prefetch for ks+1
            const _Float16* src = wt + (size_t)(ks + 1) * 4096 + tid * 16;
            gn0 = *(const f16x8*)src;
            gn1 = *(const f16x8*)(src + 8);
        }
        const int buf = ks & 1;
        const int tap = ks >> 2, kc = ks & 3;
        const int koff = kc * 32 + quad * 8;
        const _Float16* bb = &Bls[buf][boff];
#pragma unroll
        for (int r = 0; r < 4; ++r) {
            f16x8 af = *(const f16x8*)&Al[((DR[tap] + r0 + r) * 18 + DP[tap] + l16) * 136 + koff];
#pragma unroll
            for (int nf = 0; nf < 4; ++nf) {
                f16x8 bf = *(const f16x8*)(bb + nf * 640);
                acc[r][nf] = __builtin_amdgcn_mfma_f32_16x16x32_f16(af, bf, acc[r][nf], 0, 0, 0);
            }
        }
        if (ks < 19) {                           // commit prefetch to other buffer
            _Float16* dst = &Bls[buf ^ 1][(tid >> 1) * 40 + (tid & 1) * 16];
            *(f16x8*)dst = gn0;
            *(f16x8*)(dst + 8) = gn1;
            __syncthreads();
        }
    }

#pragma unroll
    for (int r = 0; r < 4; ++r) {
        const size_t rowb = ((size_t)b * 256 + i0 + r0 + r) * 256 + j0;
#pragma unroll
        for (int nf = 0; nf < 4; ++nf) {
            const float bv = bias[n0 + nf * 16 + l16];
#pragma unroll
            for (int vi = 0; vi < 4; ++vi)
                outp[(rowb + quad * 4 + vi) * 128 + n0 + nf * 16 + l16] =
                    (_Float16)fmaxf(acc[r][nf][vi] + bv, 0.f);
        }
    }
}

// ---------------- L4: 128 -> 6 (pad 16), MFMA, fp32 NCHW out ----------------
__global__ __launch_bounds__(256, 3) void g4(
    const _Float16* __restrict__ in, const float* __restrict__ bias,
    float* __restrict__ outp)
{
    __shared__ _Float16 Al[6 * 18 * 136];
    const int tid = threadIdx.x;
    const int jt = blockIdx.x, it = blockIdx.y, b = blockIdx.z;
    const int i0 = it * 4, j0 = jt * 16;

    for (int t = tid; t < 6 * 18 * 16; t += 256) {
        int r = t / 288, rem = t % 288, p = rem >> 4, q = rem & 15;
        int gi = i0 - 1 + r, gj = j0 - 1 + p;
        f16x8 v = {0, 0, 0, 0, 0, 0, 0, 0};
        if (((unsigned)gi < 256u) && ((unsigned)gj < 256u))
            v = *(const f16x8*)&in[(((size_t)b * 256 + gi) * 256 + gj) * 128 + q * 8];
        *(f16x8*)&Al[(r * 18 + p) * 136 + q * 8] = v;
    }
    __syncthreads();

    const int lane = tid & 63, wid = tid >> 6;
    const int l16 = lane & 15, quad = lane >> 4;
    f32x4 acc = {};
    const int DR[5] = {1, 0, 2, 1, 1}, DP[5] = {1, 1, 1, 0, 2};

#pragma unroll
    for (int ks = 0; ks < 20; ++ks) {
        const int tap = ks >> 2, kc = ks & 3;
        const int koff = kc * 32 + quad * 8;
        f16x8 bf = *(const f16x8*)&W4g[(size_t)(tap * 16 + l16) * 128 + koff];
        f16x8 af = *(const f16x8*)&Al[((DR[tap] + wid) * 18 + DP[tap] + l16) * 136 + koff];
        acc = __builtin_amdgcn_mfma_f32_16x16x32_f16(af, bf, acc, 0, 0, 0);
    }

    if (l16 < 6) {
        const float bb = bias[l16];
        const int i = i0 + wid;
#pragma unroll
        for (int vi = 0; vi < 4; ++vi) {
            int jj = j0 + quad * 4 + vi;
            outp[(((size_t)b * 6 + l16) << 16) + i * 256 + jj] = acc[vi] + bb;
        }
    }
}

extern "C" void kernel_launch(void* const* d_in, const int* in_sizes, int n_in,
                              void* d_out, int out_size, void* d_ws, size_t ws_size,
                              hipStream_t stream) {
    const float* x  = (const float*)d_in[0];
    const float* w1 = (const float*)d_in[1];
    const float* b1 = (const float*)d_in[2];
    const float* w2 = (const float*)d_in[3];
    const float* b2 = (const float*)d_in[4];
    const float* w3 = (const float*)d_in[5];
    const float* b3 = (const float*)d_in[6];
    const float* w4 = (const float*)d_in[7];
    const float* b4 = (const float*)d_in[8];
    float* out = (float*)d_out;

    const size_t act = (size_t)BB * HH * WW * 128;
    _Float16* A1 = (_Float16*)d_ws;
    _Float16* A2 = A1 + act;                    // exactly 268435456 B total

    prep<<<696, 256, 0, stream>>>(w1, w2, w3, w4);
    dim3 blk(256, 1, 1);
    dim3 gm(16, 32, 8);                         // 16-px x 8-row tiles
    g1<<<gm, blk, 0, stream>>>(x, b1, A1);
    gmid<2><<<gm, blk, 0, stream>>>(A1, b2, A2);
    gmid<3><<<gm, blk, 0, stream>>>(A2, b3, A1);
    g4<<<dim3(16, 64, 8), blk, 0, stream>>>(A1, b4, out);
}